// Round 4
// baseline (26.410 us; speedup 1.0000x reference)
//
#include <hip/hip_runtime.h>

#define ROWS 128
#define COLS 128
#define NIMG 32
#define NG   128
#define PIX  (ROWS * COLS)

typedef float v2f __attribute__((ext_vector_type(2)));
typedef float v8f __attribute__((ext_vector_type(8)));
// Constant-address-space view of packed params -> uniform loads become
// s_load_dwordx8 through the scalar cache.
typedef const __attribute__((address_space(4))) v8f cv8f;

// q2(x,y) = a2*x^2 + b2*y^2 + c2*x*y + P*x + Q*y + R  ( = -0.5*log2e * q )
// out[n,r,c] = sum_g amp * exp2(q2(lin[c], lin[r]))
__global__ __launch_bounds__(256) void rbf_prepass(
    const float* __restrict__ centers,   // (NIMG, NG, 2)
    const float* __restrict__ covs,      // (NIMG, NG, 3)
    const float* __restrict__ amps,      // (NIMG, NG, 1)
    float* __restrict__ params)          // (NIMG*NG, 8)
{
    int j = blockIdx.x * 256 + threadIdx.x;
    if (j >= NIMG * NG) return;
    const float ka = -0.72134752044448170368f;   // -0.5*log2(e)
    const float kc = -1.44269504088896340736f;   // -log2(e)
    float cx = centers[j * 2 + 0];
    float cy = centers[j * 2 + 1];
    float a2 = ka * covs[j * 3 + 0];
    float b2 = ka * covs[j * 3 + 1];
    float c2 = kc * covs[j * 3 + 2];
    float am = amps[j];
    float P = -2.0f * a2 * cx - c2 * cy;
    float Q = -2.0f * b2 * cy - c2 * cx;
    float R = a2 * cx * cx + b2 * cy * cy + c2 * cx * cy;
    float* o = params + j * 8;
    o[0] = a2; o[1] = b2; o[2] = c2; o[3] = P;
    o[4] = Q;  o[5] = R;  o[6] = am; o[7] = 0.0f;
}

// ---- main: 2 pixels/thread (rows r0, r0+64), 1024 blocks = 4/CU ----------
__global__ __launch_bounds__(256) void rbf_main2(
    const float* __restrict__ params,    // (NIMG*NG, 8)
    float* __restrict__ out)             // (NIMG, ROWS, COLS)
{
    const int img  = blockIdx.x >> 5;        // 32 blocks of 512 px per image
    const int tile = blockIdx.x & 31;
    const int t    = threadIdx.x;

    const int p0 = tile * 256 + t;           // r0*COLS + c, r0 in [0,64)
    const int r0 = p0 >> 7;
    const int c  = p0 & 127;
    const float step = 2.0f / 127.0f;
    const float x  = -1.0f + step * (float)c;
    const float y0 = -1.0f + step * (float)r0;
    const float y1 = y0 + 64.0f * step;      // row r0 + 64

    const v2f Y = { y0, y1 };

    cv8f* qp = (cv8f*)(size_t)(params + (size_t)img * NG * 8);

    v2f acc = { 0.0f, 0.0f };

    #pragma unroll 4
    for (int g = 0; g < NG; ++g) {
        v8f gp = qp[g];                      // s_load_dwordx8 (uniform)
        float a2 = gp[0], b2 = gp[1], c2 = gp[2];
        float Pc = gp[3], Qc = gp[4], R  = gp[5];
        float am = gp[6];

        float base = __builtin_fmaf(__builtin_fmaf(a2, x, Pc), x, R);
        float u    = __builtin_fmaf(c2, x, Qc);

        v2f b2v = { b2, b2 };
        v2f uv  = { u,  u  };
        v2f bv  = { base, base };
        v2f amv = { am, am };

        v2f tq = b2v * Y + uv;               // b2*y + u
        v2f q  = tq * Y + bv;                // (b2*y+u)*y + base
        v2f e  = { __builtin_amdgcn_exp2f(q.x), __builtin_amdgcn_exp2f(q.y) };
        acc = amv * e + acc;
    }

    float* o = out + (size_t)img * PIX + p0;
    o[0]         = acc.x;                    // row r0
    o[64 * 128]  = acc.y;                    // row r0 + 64
}

// ---------------- fallback (LDS broadcast, 1 px/thread) --------------------
__global__ __launch_bounds__(256) void rbf_fallback(
    const float* __restrict__ centers,
    const float* __restrict__ covs,
    const float* __restrict__ amps,
    float* __restrict__ out)
{
    __shared__ float4 sp0[NG];
    __shared__ float2 sp1[NG];
    const int img  = blockIdx.x >> 6;
    const int tile = blockIdx.x & 63;
    const int t    = threadIdx.x;
    if (t < NG) {
        const float LOG2E = 1.44269504088896340736f;
        int base = img * NG + t;
        float cx = centers[base * 2 + 0];
        float cy = centers[base * 2 + 1];
        float a  = covs[base * 3 + 0];
        float b  = covs[base * 3 + 1];
        float cc = covs[base * 3 + 2];
        float am = amps[base];
        sp0[t] = make_float4(cx, cy, -0.5f * LOG2E * a, -LOG2E * cc);
        sp1[t] = make_float2(-0.5f * LOG2E * b, am);
    }
    __syncthreads();
    const int p = tile * 256 + t;
    const int r = p >> 7;
    const int c = p & 127;
    const float step = 2.0f / 127.0f;
    const float xc = -1.0f + step * (float)c;
    const float yr = -1.0f + step * (float)r;
    float acc = 0.0f;
    #pragma unroll 8
    for (int g = 0; g < NG; ++g) {
        float4 p0 = sp0[g];
        float2 p1 = sp1[g];
        float dx = xc - p0.x;
        float dy = yr - p0.y;
        float t1 = p0.z * dx + p0.w * dy;
        float t2 = p1.x * dy;
        float q2 = t1 * dx + t2 * dy;
        acc += p1.y * __builtin_amdgcn_exp2f(q2);
    }
    out[img * PIX + p] = acc;
}

extern "C" void kernel_launch(void* const* d_in, const int* in_sizes, int n_in,
                              void* d_out, int out_size, void* d_ws, size_t ws_size,
                              hipStream_t stream) {
    const float* centers = (const float*)d_in[0];
    const float* covs    = (const float*)d_in[1];
    const float* amps    = (const float*)d_in[2];
    float* out           = (float*)d_out;

    const size_t need = (size_t)NIMG * NG * 8 * sizeof(float);  // 128 KiB
    if (ws_size >= need) {
        float* params = (float*)d_ws;
        rbf_prepass<<<dim3((NIMG * NG + 255) / 256), dim3(256), 0, stream>>>(
            centers, covs, amps, params);
        rbf_main2<<<dim3(NIMG * (PIX / 512)), dim3(256), 0, stream>>>(params, out);
    } else {
        rbf_fallback<<<dim3(NIMG * (PIX / 256)), dim3(256), 0, stream>>>(
            centers, covs, amps, out);
    }
}

// Round 5
// 19.230 us; speedup vs baseline: 1.3734x; 1.3734x over previous
//
#include <hip/hip_runtime.h>

#define ROWS 128
#define COLS 128
#define NIMG 32
#define NG   128
#define PIX  (ROWS * COLS)

typedef float v2f __attribute__((ext_vector_type(2)));

// out[n,r,c] = sum_g amp * exp2( a2*x^2 + b2*y^2 + c2*x*y + P*x + Q*y + R )
//   x = lin[c], y = lin[r], lin[i] = -1 + 2i/127; coefs pre-scaled by -0.5*log2e.
// Single fused kernel: each block computes the packed poly params for its
// image into LDS (redundantly per block - 128 gaussians, trivial cost), then
// evaluates 512 pixels (2 per thread: rows r0 and r0+64, same column).
__global__ __launch_bounds__(256) void rbf_fused(
    const float* __restrict__ centers,   // (NIMG, NG, 2)
    const float* __restrict__ covs,      // (NIMG, NG, 3)
    const float* __restrict__ amps,      // (NIMG, NG, 1)
    float* __restrict__ out)             // (NIMG, ROWS, COLS)
{
    __shared__ float4 s0[NG];  // a2, b2, c2, P
    __shared__ float4 s1[NG];  // Q,  R,  am, 0

    const int img  = blockIdx.x >> 5;        // 32 blocks of 512 px per image
    const int tile = blockIdx.x & 31;
    const int t    = threadIdx.x;

    if (t < NG) {
        const float ka = -0.72134752044448170368f;   // -0.5*log2(e)
        const float kc = -1.44269504088896340736f;   // -log2(e)
        int j = img * NG + t;
        float cx = centers[j * 2 + 0];
        float cy = centers[j * 2 + 1];
        float a2 = ka * covs[j * 3 + 0];
        float b2 = ka * covs[j * 3 + 1];
        float c2 = kc * covs[j * 3 + 2];
        float am = amps[j];
        float P = -2.0f * a2 * cx - c2 * cy;
        float Q = -2.0f * b2 * cy - c2 * cx;
        float R = __builtin_fmaf(a2 * cx, cx,
                  __builtin_fmaf(b2 * cy, cy, c2 * cx * cy));
        s0[t] = make_float4(a2, b2, c2, P);
        s1[t] = make_float4(Q, R, am, 0.0f);
    }
    __syncthreads();

    const int p0 = tile * 256 + t;           // r0*COLS + c, r0 in [0,64)
    const int r0 = p0 >> 7;
    const int c  = p0 & 127;
    const float step = 2.0f / 127.0f;
    const float x  = -1.0f + step * (float)c;
    const float y0 = -1.0f + step * (float)r0;
    const float y1 = y0 + 64.0f * step;      // row r0 + 64

    const v2f Y = { y0, y1 };

    v2f acc = { 0.0f, 0.0f };

    #pragma unroll 8
    for (int g = 0; g < NG; ++g) {
        float4 g0 = s0[g];                   // broadcast ds_read_b128
        float4 g1 = s1[g];
        float a2 = g0.x, b2 = g0.y, c2 = g0.z, P = g0.w;
        float Q  = g1.x, R  = g1.y, am = g1.z;

        float base = __builtin_fmaf(__builtin_fmaf(a2, x, P), x, R);
        float u    = __builtin_fmaf(c2, x, Q);

        v2f b2v = { b2, b2 };
        v2f uv  = { u,  u  };
        v2f bv  = { base, base };
        v2f amv = { am, am };

        v2f tq = b2v * Y + uv;               // b2*y + u
        v2f q  = tq * Y + bv;                // (b2*y+u)*y + base
        v2f e  = { __builtin_amdgcn_exp2f(q.x), __builtin_amdgcn_exp2f(q.y) };
        acc = amv * e + acc;
    }

    float* o = out + (size_t)img * PIX + p0;
    o[0]        = acc.x;                     // row r0
    o[64 * 128] = acc.y;                     // row r0 + 64
}

extern "C" void kernel_launch(void* const* d_in, const int* in_sizes, int n_in,
                              void* d_out, int out_size, void* d_ws, size_t ws_size,
                              hipStream_t stream) {
    const float* centers = (const float*)d_in[0];
    const float* covs    = (const float*)d_in[1];
    const float* amps    = (const float*)d_in[2];
    float* out           = (float*)d_out;

    rbf_fused<<<dim3(NIMG * (PIX / 512)), dim3(256), 0, stream>>>(
        centers, covs, amps, out);
}

// Round 6
// 17.165 us; speedup vs baseline: 1.5386x; 1.1203x over previous
//
#include <hip/hip_runtime.h>

#define ROWS 128
#define COLS 128
#define NIMG 32
#define NG   128
#define PIX  (ROWS * COLS)

typedef float v2f __attribute__((ext_vector_type(2)));

// out[n,r,c] = sum_g amp * exp2( a2*x^2 + b2*y^2 + c2*x*y + P*x + Q*y + R )
//   x = lin[c], y = lin[r], lin[i] = -1 + 2i/127; coefs pre-scaled by -0.5*log2e.
// Single fused kernel, 4 pixels/thread (same column; rows r0, r0+32, +64, +96).
// Per-block LDS param build is redundant across the 16 blocks of an image but
// costs ~128x20 VALU once vs 128-iter main loop.
__global__ __launch_bounds__(256) void rbf_fused4(
    const float* __restrict__ centers,   // (NIMG, NG, 2)
    const float* __restrict__ covs,      // (NIMG, NG, 3)
    const float* __restrict__ amps,      // (NIMG, NG, 1)
    float* __restrict__ out)             // (NIMG, ROWS, COLS)
{
    __shared__ float4 s0[NG];  // a2, b2, c2, P
    __shared__ float4 s1[NG];  // Q,  R,  am, 0

    const int img  = blockIdx.x >> 4;        // 16 blocks of 1024 px per image
    const int tile = blockIdx.x & 15;
    const int t    = threadIdx.x;

    if (t < NG) {
        const float ka = -0.72134752044448170368f;   // -0.5*log2(e)
        const float kc = -1.44269504088896340736f;   // -log2(e)
        int j = img * NG + t;
        float cx = centers[j * 2 + 0];
        float cy = centers[j * 2 + 1];
        float a2 = ka * covs[j * 3 + 0];
        float b2 = ka * covs[j * 3 + 1];
        float c2 = kc * covs[j * 3 + 2];
        float am = amps[j];
        float P = -2.0f * a2 * cx - c2 * cy;
        float Q = -2.0f * b2 * cy - c2 * cx;
        float R = __builtin_fmaf(a2 * cx, cx,
                  __builtin_fmaf(b2 * cy, cy, c2 * cx * cy));
        s0[t] = make_float4(a2, b2, c2, P);
        s1[t] = make_float4(Q, R, am, 0.0f);
    }
    __syncthreads();

    const int p0 = tile * 256 + t;           // r0*COLS + c, r0 in [0,32)
    const int r0 = p0 >> 7;
    const int c  = p0 & 127;
    const float step = 2.0f / 127.0f;
    const float x  = -1.0f + step * (float)c;
    const float y0 = -1.0f + step * (float)r0;

    const v2f Ya = { y0,                y0 + 32.0f * step };
    const v2f Yb = { y0 + 64.0f * step, y0 + 96.0f * step };

    v2f accA = { 0.0f, 0.0f };
    v2f accB = { 0.0f, 0.0f };

    #pragma unroll 8
    for (int g = 0; g < NG; ++g) {
        float4 g0 = s0[g];                   // broadcast ds_read_b128
        float4 g1 = s1[g];
        float a2 = g0.x, b2 = g0.y, c2 = g0.z, P = g0.w;
        float Q  = g1.x, R  = g1.y, am = g1.z;

        float base = __builtin_fmaf(__builtin_fmaf(a2, x, P), x, R);
        float u    = __builtin_fmaf(c2, x, Q);

        v2f b2v = { b2, b2 };
        v2f uv  = { u,  u  };
        v2f bv  = { base, base };
        v2f amv = { am, am };

        v2f tA = b2v * Ya + uv;              // b2*y + u
        v2f tB = b2v * Yb + uv;
        v2f qA = tA * Ya + bv;               // (b2*y+u)*y + base
        v2f qB = tB * Yb + bv;

        v2f eA = { __builtin_amdgcn_exp2f(qA.x), __builtin_amdgcn_exp2f(qA.y) };
        v2f eB = { __builtin_amdgcn_exp2f(qB.x), __builtin_amdgcn_exp2f(qB.y) };

        accA = amv * eA + accA;
        accB = amv * eB + accB;
    }

    float* o = out + (size_t)img * PIX + p0;
    o[0]        = accA.x;                    // row r0
    o[32 * 128] = accA.y;                    // row r0+32
    o[64 * 128] = accB.x;                    // row r0+64
    o[96 * 128] = accB.y;                    // row r0+96
}

extern "C" void kernel_launch(void* const* d_in, const int* in_sizes, int n_in,
                              void* d_out, int out_size, void* d_ws, size_t ws_size,
                              hipStream_t stream) {
    const float* centers = (const float*)d_in[0];
    const float* covs    = (const float*)d_in[1];
    const float* amps    = (const float*)d_in[2];
    float* out           = (float*)d_out;

    rbf_fused4<<<dim3(NIMG * (PIX / 1024)), dim3(256), 0, stream>>>(
        centers, covs, amps, out);
}